// Round 6
// baseline (1380.891 us; speedup 1.0000x reference)
//
#include <hip/hip_runtime.h>

// Problem constants
#define B_   128
#define T_   512
#define EMB_ 128
#define H_   128
#define NL_  9
#define MT_  65536  // B*T

typedef __attribute__((ext_vector_type(8))) short short8v;
typedef __attribute__((ext_vector_type(4))) float float4v;

__device__ inline unsigned short f2bf(float f){
  unsigned u = __float_as_uint(f);
  u += 0x7FFFu + ((u >> 16) & 1u);          // round-to-nearest-even
  return (unsigned short)(u >> 16);
}
__device__ inline float bf2f(unsigned short s){
  return __uint_as_float(((unsigned)s) << 16);
}
__device__ inline float sigm(float x){ return 1.f / (1.f + __expf(-x)); }
__device__ inline float tanh_(float x){ return 2.f / (1.f + __expf(-2.f * x)) - 1.f; }

__device__ inline void gload16(const void* g, void* l){
  __builtin_amdgcn_global_load_lds(
      (const __attribute__((address_space(1))) void*)g,
      (__attribute__((address_space(3)))       void*)l, 16, 0, 0);
}

// ---------------------------------------------------------------- K0: weight prep
// Row permutation nd = j*4 + g  (g: 0=i,1=f,2=g,3=o ; original row g*128+j).
// Wih2[dir][nd][128], Whh2[dir][nd][128] bf16 ; biasc[dir][nd] = bih+bhh.
__global__ void k0_prep(const float* __restrict__ Wihf, const float* __restrict__ Whhf,
                        const float* __restrict__ bihf, const float* __restrict__ bhhf,
                        const float* __restrict__ Wihb, const float* __restrict__ Whhb,
                        const float* __restrict__ bihb, const float* __restrict__ bhhb,
                        unsigned short* __restrict__ Wih2, unsigned short* __restrict__ Whh2,
                        float* __restrict__ biasc){
  int blk = blockIdx.x;            // 0..1023
  int dir = blk >> 9;
  int nd  = blk & 511;
  int k   = threadIdx.x;           // 0..127
  int j = nd >> 2, g = nd & 3;
  int orig = g * 128 + j;
  const float* Wih = dir ? Wihb : Wihf;
  const float* Whh = dir ? Whhb : Whhf;
  Wih2[((long)(dir * 512 + nd)) * 128 + k] = f2bf(Wih[orig * EMB_ + k]);
  Whh2[((long)(dir * 512 + nd)) * 128 + k] = f2bf(Whh[orig * H_ + k]);
  if (k == 0){
    const float* bi = dir ? bihb : bihf;
    const float* bh = dir ? bhhb : bhhf;
    biasc[dir * 512 + nd] = bi[orig] + bh[orig];
  }
}

// ---------------------------------------------------------------- K1: embedding gather -> bf16
__global__ void k1_embed(const int* __restrict__ chars, const float* __restrict__ emb,
                         unsigned short* __restrict__ x){
  int i = blockIdx.x * blockDim.x + threadIdx.x;  // 2,097,152 total (each does 4 elems)
  int m = i >> 5, q = i & 31;
  int c = chars[m];
  const float4* e4 = (const float4*)(emb + (long)c * EMB_);
  float4 v = e4[q];
  ushort4 o;
  o.x = f2bf(v.x); o.y = f2bf(v.y); o.z = f2bf(v.z); o.w = f2bf(v.w);
  *(ushort4*)(x + (long)m * EMB_ + q * 4) = o;
}

// ---------------------------------------------------------------- K2: input projection GEMM (MFMA)
// G[m][n] = sum_k x[m][k]*Wih2[n][k] + biasc[n]  (m: B*T, n: 1024 = dir*512+nd, k: 128)
__global__ __launch_bounds__(256) void k2_gemm(const unsigned short* __restrict__ x,
                                               const unsigned short* __restrict__ Wih2,
                                               const float* __restrict__ biasc,
                                               unsigned short* __restrict__ G){
  int w = threadIdx.x >> 6, lane = threadIdx.x & 63;
  int r = lane & 15, kb = (lane >> 4) * 8;
  long arow = (long)(blockIdx.x * 64 + w * 16 + r);
  short8v a[4];
  #pragma unroll
  for (int kf = 0; kf < 4; kf++)
    a[kf] = *(const short8v*)(x + arow * EMB_ + kf * 32 + kb);
  int ncol0 = blockIdx.y * 128;
  float4v acc[8];
  #pragma unroll
  for (int nf = 0; nf < 8; nf++){
    float4v z = {0.f, 0.f, 0.f, 0.f};
    acc[nf] = z;
    int wrow = ncol0 + nf * 16 + r;
    #pragma unroll
    for (int kf = 0; kf < 4; kf++){
      short8v bfrag = *(const short8v*)(Wih2 + (long)wrow * 128 + kf * 32 + kb);
      acc[nf] = __builtin_amdgcn_mfma_f32_16x16x32_bf16(a[kf], bfrag, acc[nf], 0, 0, 0);
    }
  }
  int crow0 = blockIdx.x * 64 + w * 16 + (lane >> 4) * 4;
  #pragma unroll
  for (int nf = 0; nf < 8; nf++){
    int col = ncol0 + nf * 16 + r;
    float bia = biasc[col];
    #pragma unroll
    for (int reg = 0; reg < 4; reg++)
      G[(long)(crow0 + reg) * 1024 + col] = f2bf(acc[nf][reg] + bia);
  }
}

// ---------------------------------------------------------------- K3: recurrent scan (MFMA, K=128)
// 16 blocks: dir = blk>>3, batch rows [b0,b0+16). 8 waves; wave w owns hidden
// cols [16w,16w+16), all four gates (Whh slice = 64 VGPR, trivially resident).
// Gate preactivations Gpre staged 1 step ahead into LDS via global_load_lds.
#define ASTR  136   // hA slice stride (u16)
#define GSTR  520   // Gpre LDS row stride (u16): 512 data + 8 pad
#define HBSTR 136   // hbuf m stride (u16)
__global__ __launch_bounds__(512, 2) void k3_scan2(
    const unsigned short* __restrict__ G,     // [B*T][1024] bf16 (bias included)
    const unsigned short* __restrict__ Whh2,  // [2][512 nd][128] bf16
    unsigned short* __restrict__ hs)          // [2][B*T][128] bf16
{
  const int blk = blockIdx.x;        // 0..15
  const int dir = blk >> 3;
  const int b0  = (blk & 7) * 16;
  const int tid = threadIdx.x;
  const int w   = tid >> 6;          // wave 0..7
  const int l   = tid & 63;
  const int r   = l & 15;
  const int q   = l >> 4;
  const int jcol = w * 16 + r;       // hidden index owned by this lane

  __shared__ unsigned short hA[2][16 * ASTR];     // h as A-fragments, dbuf
  __shared__ unsigned short Gl[2][16 * GSTR];     // Gpre tiles, dbuf
  __shared__ unsigned short hbuf[8][16 * HBSTR];  // output ring (8 steps)

  // ---- Whh fragments: 4 gates x 4 K-slices = 64 VGPR
  short8v Bf[4][4];
  #pragma unroll
  for (int g = 0; g < 4; g++){
    const unsigned short* wp = Whh2 + ((long)(dir * 512 + jcol * 4 + g)) * 128 + q * 8;
    #pragma unroll
    for (int kf = 0; kf < 4; kf++)
      Bf[g][kf] = *(const short8v*)(wp + kf * 32);
  }
  #pragma unroll
  for (int g = 0; g < 4; g++){
    #pragma unroll
    for (int kf = 0; kf < 4; kf++)
      asm volatile("" : "+v"(Bf[g][kf]));
  }

  for (int i = tid; i < 16 * ASTR; i += 512) hA[0][i] = 0;

  float cc[4] = {0.f, 0.f, 0.f, 0.f};
  const int hAoff = (jcol >> 3) * ASTR + (jcol & 7);

  // prologue: stage Gpre for s=0 (wave w loads rows 2w, 2w+1; 1KB each)
  {
    int t0 = dir ? (T_ - 1) : 0;
    #pragma unroll
    for (int i = 0; i < 2; i++){
      int row = 2 * w + i;
      const unsigned short* src = G + ((long)(b0 + row) * T_ + t0) * 1024 + dir * 512 + l * 8;
      gload16(src, &Gl[0][row * GSTR]);
    }
  }
  __syncthreads();

  for (int s = 0; s < T_; s++){
    const int p = s & 1;
    // stage Gpre for s+1 (drained by this step's __syncthreads -> 1 step of cover)
    if (s + 1 < T_){
      int tn = dir ? (T_ - 2 - s) : (s + 1);
      #pragma unroll
      for (int i = 0; i < 2; i++){
        int row = 2 * w + i;
        const unsigned short* src = G + ((long)(b0 + row) * T_ + tn) * 1024 + dir * 512 + l * 8;
        gload16(src, &Gl[p ^ 1][row * GSTR]);
      }
    }

    // ---- MFMA: gacc = h @ Whh^T  (K=128)
    float4v acc[4];
    #pragma unroll
    for (int g = 0; g < 4; g++){ float4v z = {0.f,0.f,0.f,0.f}; acc[g] = z; }
    #pragma unroll
    for (int kf = 0; kf < 4; kf++){
      short8v af = *(const short8v*)&hA[p][(kf * 4 + q) * ASTR + r * 8];
      #pragma unroll
      for (int g = 0; g < 4; g++)
        acc[g] = __builtin_amdgcn_mfma_f32_16x16x32_bf16(af, Bf[g][kf], acc[g], 0, 0, 0);
    }

    // ---- gates: Gpre (bias included) + h-recurrence; state update in-register
    #pragma unroll
    for (int reg = 0; reg < 4; reg++){
      int m = q * 4 + reg;
      ushort4 gp = *(const ushort4*)&Gl[p][m * GSTR + jcol * 4];
      float iv = sigm (acc[0][reg] + bf2f(gp.x));
      float fv = sigm (acc[1][reg] + bf2f(gp.y));
      float gg = tanh_(acc[2][reg] + bf2f(gp.z));
      float ov = sigm (acc[3][reg] + bf2f(gp.w));
      cc[reg] = fv * cc[reg] + iv * gg;
      float hv = ov * tanh_(cc[reg]);
      unsigned short hb = f2bf(hv);
      hA[p ^ 1][hAoff + m * 8] = hb;          // A-fragment for next step
      hbuf[s & 7][m * HBSTR + jcol] = hb;     // output ring
    }
    __syncthreads();

    // ---- coalesced flush of 8 steps of h
    if ((s & 7) == 7){
      #pragma unroll
      for (int mr = 0; mr < 4; mr++){
        int u  = tid + mr * 512;              // 0..2047 units of 8 elems
        int j8 = u & 15, mm = (u >> 4) & 15, ii = u >> 8;
        int sg = s - 7 + ii;
        int tg = dir ? (T_ - 1 - sg) : sg;
        short8v v = *(const short8v*)&hbuf[ii][mm * HBSTR + j8 * 8];
        *(short8v*)(hs + ((long)dir * MT_ + (long)(b0 + mm) * T_ + tg) * H_ + j8 * 8) = v;
      }
      __syncthreads();
    }
  }
}

// ---------------------------------------------------------------- K4: emissions = [hf,hb] @ Wout^T + bout
#define HSTR 264
__global__ __launch_bounds__(512) void k4_emis(const unsigned short* __restrict__ hs,
                                               const float* __restrict__ Wout,
                                               const float* __restrict__ bout,
                                               float* __restrict__ em){
  __shared__ float hcat[64 * HSTR];
  __shared__ float wo[NL_ * 256];
  int tid = threadIdx.x;
  int m0 = blockIdx.x * 64;
  const unsigned short* hf = hs;
  const unsigned short* hb = hs + (long)MT_ * H_;
  #pragma unroll
  for (int it = 0; it < 8; it++){
    int flat = it * 2048 + tid * 4;       // over 64*256 = 16384 elements
    int r = flat >> 8, u = flat & 255;
    const unsigned short* src = (u < 128) ? (hf + (long)(m0 + r) * H_ + u)
                                          : (hb + (long)(m0 + r) * H_ + (u - 128));
    ushort4 v = *(const ushort4*)src;
    hcat[r * HSTR + u]     = bf2f(v.x);
    hcat[r * HSTR + u + 1] = bf2f(v.y);
    hcat[r * HSTR + u + 2] = bf2f(v.z);
    hcat[r * HSTR + u + 3] = bf2f(v.w);
  }
  for (int f = tid; f < NL_ * 256; f += 512) wo[f] = Wout[f];
  __syncthreads();
  #pragma unroll
  for (int half = 0; half < 2; half++){
    int idx = half * 512 + tid;
    if (idx < 64 * NL_){
      int r = idx / NL_, lbl = idx % NL_;
      float acc = bout[lbl];
      #pragma unroll 8
      for (int u = 0; u < 256; u++)
        acc = fmaf(hcat[r * HSTR + u], wo[lbl * 256 + u], acc);
      em[(long)(m0 + r) * NL_ + lbl] = acc;
    }
  }
}

// ---------------------------------------------------------------- K5: CRF NLL per sequence
__global__ void k5_crf(const float* __restrict__ em, const int* __restrict__ chars,
                       const int* __restrict__ labels, const float* __restrict__ startv,
                       const float* __restrict__ endv, const float* __restrict__ trans,
                       float* __restrict__ partial){
  int b = blockIdx.x, lane = threadIdx.x;   // 64 threads (1 wave)
  const int* lab = labels + b * T_;
  const int* ch  = chars + b * T_;
  const float* e = em + (long)b * T_ * NL_;
  // --- score (parallel over t) ---
  float sc = 0.f; int cnt = 0;
  for (int t = lane; t < T_; t += 64){
    int m = (ch[t] != 0);
    cnt += m;
    if (m){
      sc += e[t * NL_ + lab[t]];
      if (t > 0) sc += trans[lab[t - 1] * NL_ + lab[t]];
    }
  }
  #pragma unroll
  for (int off = 32; off; off >>= 1){
    sc  += __shfl_down(sc, off);
    cnt += __shfl_down(cnt, off);
  }
  sc  = __shfl(sc, 0);
  cnt = __shfl(cnt, 0);
  if (cnt < 1) cnt = 1;
  // --- forward algorithm: lanes 0..8 hold alpha; emissions prefetched 1 step ahead ---
  int jl = (lane < NL_) ? lane : 0;
  float tcol[NL_];
  #pragma unroll
  for (int i = 0; i < NL_; i++) tcol[i] = trans[i * NL_ + jl];
  float alpha = (lane < NL_) ? (startv[jl] + e[jl]) : -1e30f;
  float evn = (lane < NL_) ? e[NL_ + jl] : 0.f;
  int   mn  = (ch[1] != 0);
  for (int t = 1; t < T_; t++){
    float ev = evn; int m = mn;
    int t2 = (t + 1 < T_) ? t + 1 : t;
    evn = (lane < NL_) ? e[t2 * NL_ + jl] : 0.f;
    mn  = (ch[t2] != 0);
    float vv[NL_]; float mx = -1e30f;
    #pragma unroll
    for (int i = 0; i < NL_; i++){
      vv[i] = __shfl(alpha, i) + tcol[i];
      mx = fmaxf(mx, vv[i]);
    }
    float ssum = 0.f;
    #pragma unroll
    for (int i = 0; i < NL_; i++) ssum += __expf(vv[i] - mx);
    float nxt = mx + __logf(ssum) + ev;
    if (m && lane < NL_) alpha = nxt;
  }
  float av = (lane < NL_) ? (alpha + endv[jl]) : -1e30f;
  float mx = av;
  #pragma unroll
  for (int off = 8; off; off >>= 1) mx = fmaxf(mx, __shfl_down(mx, off));
  mx = __shfl(mx, 0);
  float ex = (lane < NL_) ? __expf(av - mx) : 0.f;
  #pragma unroll
  for (int off = 8; off; off >>= 1) ex += __shfl_down(ex, off);
  if (lane == 0){
    float logZ = mx + __logf(ex);
    float score = sc + startv[lab[0]] + endv[lab[cnt - 1]];
    partial[b] = logZ - score;
  }
}

// ---------------------------------------------------------------- K6: deterministic final reduce
__global__ void k6_reduce(const float* __restrict__ partial, float* __restrict__ out){
  int lane = threadIdx.x;  // 128 threads
  float v = partial[lane];
  #pragma unroll
  for (int off = 32; off; off >>= 1) v += __shfl_down(v, off);
  __shared__ float tmp[2];
  if ((lane & 63) == 0) tmp[lane >> 6] = v;
  __syncthreads();
  if (lane == 0) out[0] = tmp[0] + tmp[1];
}

// ---------------------------------------------------------------- launch
extern "C" void kernel_launch(void* const* d_in, const int* in_sizes, int n_in,
                              void* d_out, int out_size, void* d_ws, size_t ws_size,
                              hipStream_t stream){
  const int*   chars  = (const int*)d_in[0];
  const int*   labels = (const int*)d_in[1];
  const float* emb    = (const float*)d_in[2];
  const float* Wihf   = (const float*)d_in[3];
  const float* Whhf   = (const float*)d_in[4];
  const float* bihf   = (const float*)d_in[5];
  const float* bhhf   = (const float*)d_in[6];
  const float* Wihb   = (const float*)d_in[7];
  const float* Whhb   = (const float*)d_in[8];
  const float* bihb   = (const float*)d_in[9];
  const float* bhhb   = (const float*)d_in[10];
  const float* Wout   = (const float*)d_in[11];
  const float* bout   = (const float*)d_in[12];
  const float* startv = (const float*)d_in[13];
  const float* endv   = (const float*)d_in[14];
  const float* trans  = (const float*)d_in[15];

  char* ws = (char*)d_ws;
  // em/part overlap x's region (x is dead after k2; k3 no longer reads x)
  unsigned short* x     = (unsigned short*)(ws);                   // 16,777,216 B
  float*          em    = (float*)         (ws);                   //  2,359,296 B (after k3)
  float*          part  = (float*)         (ws + 2359296);         //        512 B
  unsigned short* Wih2  = (unsigned short*)(ws + 16777216);        //    524,288 B
  unsigned short* Whh2  = (unsigned short*)(ws + 17301504);        //    524,288 B
  float*          biasc = (float*)         (ws + 17825792);        //      4,096 B
  unsigned short* G     = (unsigned short*)(ws + 17829888);        // 134,217,728 B
  unsigned short* hs    = (unsigned short*)(ws + 152047616);       //  33,554,432 B -> ends 185,602,048

  hipLaunchKernelGGL(k0_prep,  dim3(1024), dim3(128), 0, stream,
                     Wihf, Whhf, bihf, bhhf, Wihb, Whhb, bihb, bhhb, Wih2, Whh2, biasc);
  hipLaunchKernelGGL(k1_embed, dim3(8192), dim3(256), 0, stream, chars, emb, x);
  hipLaunchKernelGGL(k2_gemm,  dim3(1024, 8), dim3(256), 0, stream, x, Wih2, biasc, G);
  hipLaunchKernelGGL(k3_scan2, dim3(16),   dim3(512), 0, stream, G, Whh2, hs);
  hipLaunchKernelGGL(k4_emis,  dim3(1024), dim3(512), 0, stream, hs, Wout, bout, em);
  hipLaunchKernelGGL(k5_crf,   dim3(128),  dim3(64),  0, stream,
                     em, chars, labels, startv, endv, trans, part);
  hipLaunchKernelGGL(k6_reduce, dim3(1),   dim3(128), 0, stream, part, (float*)d_out);
}

// Round 7
// 973.858 us; speedup vs baseline: 1.4180x; 1.4180x over previous
//
#include <hip/hip_runtime.h>

// Problem constants
#define B_   128
#define T_   512
#define EMB_ 128
#define H_   128
#define NL_  9
#define MT_  65536  // B*T

typedef __attribute__((ext_vector_type(8))) short short8v;
typedef __attribute__((ext_vector_type(4))) float float4v;

__device__ inline unsigned short f2bf(float f){
  unsigned u = __float_as_uint(f);
  u += 0x7FFFu + ((u >> 16) & 1u);          // round-to-nearest-even
  return (unsigned short)(u >> 16);
}
__device__ inline float bf2f(unsigned short s){
  return __uint_as_float(((unsigned)s) << 16);
}
__device__ inline float sigm(float x){ return 1.f / (1.f + __expf(-x)); }
__device__ inline float tanh_(float x){ return 2.f / (1.f + __expf(-2.f * x)) - 1.f; }

// fast versions (v_exp_f32 = 2^x, v_rcp_f32 ~1ulp) for the hot recurrence
#define LOG2E 1.44269504f
__device__ inline float vexp2(float x){ float r; asm("v_exp_f32 %0, %1" : "=v"(r) : "v"(x)); return r; }
__device__ inline float vrcp (float x){ float r; asm("v_rcp_f32 %0, %1" : "=v"(r) : "v"(x)); return r; }
__device__ inline float sigmf_(float x){            // 1/(1+2^(-x*log2e))
  return vrcp(1.f + vexp2(-LOG2E * x));
}
__device__ inline float tanhf_(float x){            // 2/(1+2^(-2x*log2e)) - 1
  return fmaf(2.f, vrcp(1.f + vexp2(-2.f * LOG2E * x)), -1.f);
}

__device__ inline void gload16(const void* g, void* l){
  __builtin_amdgcn_global_load_lds(
      (const __attribute__((address_space(1))) void*)g,
      (__attribute__((address_space(3)))       void*)l, 16, 0, 0);
}

// ---------------------------------------------------------------- K0: weight prep
// Row permutation nd = j*4 + g  (g: 0=i,1=f,2=g,3=o ; original row g*128+j).
// Wih2[dir][nd][128], Whh2[dir][nd][128] bf16 ; biasc[dir][nd] = bih+bhh.
__global__ void k0_prep(const float* __restrict__ Wihf, const float* __restrict__ Whhf,
                        const float* __restrict__ bihf, const float* __restrict__ bhhf,
                        const float* __restrict__ Wihb, const float* __restrict__ Whhb,
                        const float* __restrict__ bihb, const float* __restrict__ bhhb,
                        unsigned short* __restrict__ Wih2, unsigned short* __restrict__ Whh2,
                        float* __restrict__ biasc){
  int blk = blockIdx.x;            // 0..1023
  int dir = blk >> 9;
  int nd  = blk & 511;
  int k   = threadIdx.x;           // 0..127
  int j = nd >> 2, g = nd & 3;
  int orig = g * 128 + j;
  const float* Wih = dir ? Wihb : Wihf;
  const float* Whh = dir ? Whhb : Whhf;
  Wih2[((long)(dir * 512 + nd)) * 128 + k] = f2bf(Wih[orig * EMB_ + k]);
  Whh2[((long)(dir * 512 + nd)) * 128 + k] = f2bf(Whh[orig * H_ + k]);
  if (k == 0){
    const float* bi = dir ? bihb : bihf;
    const float* bh = dir ? bhhb : bhhf;
    biasc[dir * 512 + nd] = bi[orig] + bh[orig];
  }
}

// ---------------------------------------------------------------- K1: embedding gather -> bf16
__global__ void k1_embed(const int* __restrict__ chars, const float* __restrict__ emb,
                         unsigned short* __restrict__ x){
  int i = blockIdx.x * blockDim.x + threadIdx.x;  // 2,097,152 total (each does 4 elems)
  int m = i >> 5, q = i & 31;
  int c = chars[m];
  const float4* e4 = (const float4*)(emb + (long)c * EMB_);
  float4 v = e4[q];
  ushort4 o;
  o.x = f2bf(v.x); o.y = f2bf(v.y); o.z = f2bf(v.z); o.w = f2bf(v.w);
  *(ushort4*)(x + (long)m * EMB_ + q * 4) = o;
}

// ---------------------------------------------------------------- K2: input projection GEMM (MFMA)
// G[m][n] = sum_k x[m][k]*Wih2[n][k] + biasc[n]; LDS-staged coalesced epilogue.
#define CST 130
__global__ __launch_bounds__(256) void k2_gemm(const unsigned short* __restrict__ x,
                                               const unsigned short* __restrict__ Wih2,
                                               const float* __restrict__ biasc,
                                               unsigned short* __restrict__ G){
  __shared__ unsigned short gsm[64 * CST];
  int w = threadIdx.x >> 6, lane = threadIdx.x & 63;
  int r = lane & 15, kb = (lane >> 4) * 8;
  long arow = (long)(blockIdx.x * 64 + w * 16 + r);
  short8v a[4];
  #pragma unroll
  for (int kf = 0; kf < 4; kf++)
    a[kf] = *(const short8v*)(x + arow * EMB_ + kf * 32 + kb);
  int ncol0 = blockIdx.y * 128;
  float4v acc[8];
  #pragma unroll
  for (int nf = 0; nf < 8; nf++){
    float4v z = {0.f, 0.f, 0.f, 0.f};
    acc[nf] = z;
    int wrow = ncol0 + nf * 16 + r;
    #pragma unroll
    for (int kf = 0; kf < 4; kf++){
      short8v bfrag = *(const short8v*)(Wih2 + (long)wrow * 128 + kf * 32 + kb);
      acc[nf] = __builtin_amdgcn_mfma_f32_16x16x32_bf16(a[kf], bfrag, acc[nf], 0, 0, 0);
    }
  }
  int rloc0 = w * 16 + (lane >> 4) * 4;
  #pragma unroll
  for (int nf = 0; nf < 8; nf++){
    int col = ncol0 + nf * 16 + r;
    float bia = biasc[col];
    #pragma unroll
    for (int reg = 0; reg < 4; reg++)
      gsm[(rloc0 + reg) * CST + nf * 16 + r] = f2bf(acc[nf][reg] + bia);
  }
  __syncthreads();
  // coalesced write: 64 rows x 128 cols = 1024 x 16B units
  #pragma unroll
  for (int it = 0; it < 4; it++){
    int u = it * 256 + threadIdx.x;      // 0..1023
    int row = u >> 4, cu = u & 15;
    short8v v = *(const short8v*)&gsm[row * CST + cu * 8];
    *(short8v*)(G + (long)(blockIdx.x * 64 + row) * 1024 + ncol0 + cu * 8) = v;
  }
}

// ---------------------------------------------------------------- K3: recurrent scan (MFMA, K=128)
// 16 blocks: dir = blk>>3, batch rows [b0,b0+16). 8 waves; wave w owns hidden
// cols [16w,16w+16), all four gates. Gpre staged 1 step ahead via global_load_lds.
#define ASTR  136   // hA slice stride (u16)
#define GSTR  520   // Gpre LDS row stride (u16): 512 data + 8 pad
#define HBSTR 136   // hbuf m stride (u16)
__global__ __launch_bounds__(512, 2) void k3_scan2(
    const unsigned short* __restrict__ G,     // [B*T][1024] bf16 (bias included)
    const unsigned short* __restrict__ Whh2,  // [2][512 nd][128] bf16
    unsigned short* __restrict__ hs)          // [2][B*T][128] bf16
{
  const int blk = blockIdx.x;        // 0..15
  const int dir = blk >> 3;
  const int b0  = (blk & 7) * 16;
  const int tid = threadIdx.x;
  const int w   = tid >> 6;          // wave 0..7
  const int l   = tid & 63;
  const int r   = l & 15;
  const int q   = l >> 4;
  const int jcol = w * 16 + r;       // hidden index owned by this lane

  __shared__ unsigned short hA[2][16 * ASTR];     // h as A-fragments, dbuf
  __shared__ unsigned short Gl[2][16 * GSTR];     // Gpre tiles, dbuf
  __shared__ unsigned short hbuf[8][16 * HBSTR];  // output ring (8 steps)

  // ---- Whh fragments: 4 gates x 4 K-slices = 64 regs
  short8v Bf[4][4];
  #pragma unroll
  for (int g = 0; g < 4; g++){
    const unsigned short* wp = Whh2 + ((long)(dir * 512 + jcol * 4 + g)) * 128 + q * 8;
    #pragma unroll
    for (int kf = 0; kf < 4; kf++)
      Bf[g][kf] = *(const short8v*)(wp + kf * 32);
  }
  #pragma unroll
  for (int g = 0; g < 4; g++){
    #pragma unroll
    for (int kf = 0; kf < 4; kf++)
      asm volatile("" : "+v"(Bf[g][kf]));
  }

  for (int i = tid; i < 16 * ASTR; i += 512) hA[0][i] = 0;

  float cc[4] = {0.f, 0.f, 0.f, 0.f};
  const int hAoff = (jcol >> 3) * ASTR + (jcol & 7);

  // prologue: stage Gpre for s=0 (wave w loads rows 2w, 2w+1; 1KB each)
  {
    int t0 = dir ? (T_ - 1) : 0;
    #pragma unroll
    for (int i = 0; i < 2; i++){
      int row = 2 * w + i;
      const unsigned short* src = G + ((long)(b0 + row) * T_ + t0) * 1024 + dir * 512 + l * 8;
      gload16(src, &Gl[0][row * GSTR]);
    }
  }
  __syncthreads();

  for (int s = 0; s < T_; s++){
    const int p = s & 1;
    // stage Gpre for s+1 (drained by this step's __syncthreads -> 1 step of cover)
    if (s + 1 < T_){
      int tn = dir ? (T_ - 2 - s) : (s + 1);
      #pragma unroll
      for (int i = 0; i < 2; i++){
        int row = 2 * w + i;
        const unsigned short* src = G + ((long)(b0 + row) * T_ + tn) * 1024 + dir * 512 + l * 8;
        gload16(src, &Gl[p ^ 1][row * GSTR]);
      }
    }

    // ---- MFMA: gacc = h @ Whh^T  (K=128)
    float4v acc[4];
    #pragma unroll
    for (int g = 0; g < 4; g++){ float4v z = {0.f,0.f,0.f,0.f}; acc[g] = z; }
    #pragma unroll
    for (int kf = 0; kf < 4; kf++){
      short8v af = *(const short8v*)&hA[p][(kf * 4 + q) * ASTR + r * 8];
      #pragma unroll
      for (int g = 0; g < 4; g++)
        acc[g] = __builtin_amdgcn_mfma_f32_16x16x32_bf16(af, Bf[g][kf], acc[g], 0, 0, 0);
    }

    // ---- gates: Gpre (bias included) + h-recurrence; fast exp/rcp nonlinearities
    #pragma unroll
    for (int reg = 0; reg < 4; reg++){
      int m = q * 4 + reg;
      ushort4 gp = *(const ushort4*)&Gl[p][m * GSTR + jcol * 4];
      float iv = sigmf_(acc[0][reg] + bf2f(gp.x));
      float fv = sigmf_(acc[1][reg] + bf2f(gp.y));
      float gg = tanhf_(acc[2][reg] + bf2f(gp.z));
      float ov = sigmf_(acc[3][reg] + bf2f(gp.w));
      cc[reg] = fv * cc[reg] + iv * gg;
      float hv = ov * tanhf_(cc[reg]);
      unsigned short hb = f2bf(hv);
      hA[p ^ 1][hAoff + m * 8] = hb;          // A-fragment for next step
      hbuf[s & 7][m * HBSTR + jcol] = hb;     // output ring
    }
    __syncthreads();

    // ---- coalesced flush of 8 steps of h
    if ((s & 7) == 7){
      #pragma unroll
      for (int mr = 0; mr < 4; mr++){
        int u  = tid + mr * 512;              // 0..2047 units of 8 elems
        int j8 = u & 15, mm = (u >> 4) & 15, ii = u >> 8;
        int sg = s - 7 + ii;
        int tg = dir ? (T_ - 1 - sg) : sg;
        short8v v = *(const short8v*)&hbuf[ii][mm * HBSTR + j8 * 8];
        *(short8v*)(hs + ((long)dir * MT_ + (long)(b0 + mm) * T_ + tg) * H_ + j8 * 8) = v;
      }
      __syncthreads();
    }
  }
}

// ---------------------------------------------------------------- K4: emissions = [hf,hb] @ Wout^T + bout
#define HSTR 264
__global__ __launch_bounds__(512) void k4_emis(const unsigned short* __restrict__ hs,
                                               const float* __restrict__ Wout,
                                               const float* __restrict__ bout,
                                               float* __restrict__ em){
  __shared__ float hcat[64 * HSTR];
  __shared__ float wo[NL_ * 256];
  int tid = threadIdx.x;
  int m0 = blockIdx.x * 64;
  const unsigned short* hf = hs;
  const unsigned short* hb = hs + (long)MT_ * H_;
  #pragma unroll
  for (int it = 0; it < 8; it++){
    int flat = it * 2048 + tid * 4;       // over 64*256 = 16384 elements
    int r = flat >> 8, u = flat & 255;
    const unsigned short* src = (u < 128) ? (hf + (long)(m0 + r) * H_ + u)
                                          : (hb + (long)(m0 + r) * H_ + (u - 128));
    ushort4 v = *(const ushort4*)src;
    hcat[r * HSTR + u]     = bf2f(v.x);
    hcat[r * HSTR + u + 1] = bf2f(v.y);
    hcat[r * HSTR + u + 2] = bf2f(v.z);
    hcat[r * HSTR + u + 3] = bf2f(v.w);
  }
  for (int f = tid; f < NL_ * 256; f += 512) wo[f] = Wout[f];
  __syncthreads();
  #pragma unroll
  for (int half = 0; half < 2; half++){
    int idx = half * 512 + tid;
    if (idx < 64 * NL_){
      int r = idx / NL_, lbl = idx % NL_;
      float acc = bout[lbl];
      #pragma unroll 8
      for (int u = 0; u < 256; u++)
        acc = fmaf(hcat[r * HSTR + u], wo[lbl * 256 + u], acc);
      em[(long)(m0 + r) * NL_ + lbl] = acc;
    }
  }
}

// ---------------------------------------------------------------- K5: CRF NLL per sequence
__global__ void k5_crf(const float* __restrict__ em, const int* __restrict__ chars,
                       const int* __restrict__ labels, const float* __restrict__ startv,
                       const float* __restrict__ endv, const float* __restrict__ trans,
                       float* __restrict__ partial){
  int b = blockIdx.x, lane = threadIdx.x;   // 64 threads (1 wave)
  const int* lab = labels + b * T_;
  const int* ch  = chars + b * T_;
  const float* e = em + (long)b * T_ * NL_;
  // --- score (parallel over t) ---
  float sc = 0.f; int cnt = 0;
  for (int t = lane; t < T_; t += 64){
    int m = (ch[t] != 0);
    cnt += m;
    if (m){
      sc += e[t * NL_ + lab[t]];
      if (t > 0) sc += trans[lab[t - 1] * NL_ + lab[t]];
    }
  }
  #pragma unroll
  for (int off = 32; off; off >>= 1){
    sc  += __shfl_down(sc, off);
    cnt += __shfl_down(cnt, off);
  }
  sc  = __shfl(sc, 0);
  cnt = __shfl(cnt, 0);
  if (cnt < 1) cnt = 1;
  // --- forward algorithm: lanes 0..8 hold alpha; emissions prefetched 1 step ahead ---
  int jl = (lane < NL_) ? lane : 0;
  float tcol[NL_];
  #pragma unroll
  for (int i = 0; i < NL_; i++) tcol[i] = trans[i * NL_ + jl];
  float alpha = (lane < NL_) ? (startv[jl] + e[jl]) : -1e30f;
  float evn = (lane < NL_) ? e[NL_ + jl] : 0.f;
  int   mn  = (ch[1] != 0);
  for (int t = 1; t < T_; t++){
    float ev = evn; int m = mn;
    int t2 = (t + 1 < T_) ? t + 1 : t;
    evn = (lane < NL_) ? e[t2 * NL_ + jl] : 0.f;
    mn  = (ch[t2] != 0);
    float vv[NL_]; float mx = -1e30f;
    #pragma unroll
    for (int i = 0; i < NL_; i++){
      vv[i] = __shfl(alpha, i) + tcol[i];
      mx = fmaxf(mx, vv[i]);
    }
    float ssum = 0.f;
    #pragma unroll
    for (int i = 0; i < NL_; i++) ssum += __expf(vv[i] - mx);
    float nxt = mx + __logf(ssum) + ev;
    if (m && lane < NL_) alpha = nxt;
  }
  float av = (lane < NL_) ? (alpha + endv[jl]) : -1e30f;
  float mx = av;
  #pragma unroll
  for (int off = 8; off; off >>= 1) mx = fmaxf(mx, __shfl_down(mx, off));
  mx = __shfl(mx, 0);
  float ex = (lane < NL_) ? __expf(av - mx) : 0.f;
  #pragma unroll
  for (int off = 8; off; off >>= 1) ex += __shfl_down(ex, off);
  if (lane == 0){
    float logZ = mx + __logf(ex);
    float score = sc + startv[lab[0]] + endv[lab[cnt - 1]];
    partial[b] = logZ - score;
  }
}

// ---------------------------------------------------------------- K6: deterministic final reduce
__global__ void k6_reduce(const float* __restrict__ partial, float* __restrict__ out){
  int lane = threadIdx.x;  // 128 threads
  float v = partial[lane];
  #pragma unroll
  for (int off = 32; off; off >>= 1) v += __shfl_down(v, off);
  __shared__ float tmp[2];
  if ((lane & 63) == 0) tmp[lane >> 6] = v;
  __syncthreads();
  if (lane == 0) out[0] = tmp[0] + tmp[1];
}

// ---------------------------------------------------------------- launch
extern "C" void kernel_launch(void* const* d_in, const int* in_sizes, int n_in,
                              void* d_out, int out_size, void* d_ws, size_t ws_size,
                              hipStream_t stream){
  const int*   chars  = (const int*)d_in[0];
  const int*   labels = (const int*)d_in[1];
  const float* emb    = (const float*)d_in[2];
  const float* Wihf   = (const float*)d_in[3];
  const float* Whhf   = (const float*)d_in[4];
  const float* bihf   = (const float*)d_in[5];
  const float* bhhf   = (const float*)d_in[6];
  const float* Wihb   = (const float*)d_in[7];
  const float* Whhb   = (const float*)d_in[8];
  const float* bihb   = (const float*)d_in[9];
  const float* bhhb   = (const float*)d_in[10];
  const float* Wout   = (const float*)d_in[11];
  const float* bout   = (const float*)d_in[12];
  const float* startv = (const float*)d_in[13];
  const float* endv   = (const float*)d_in[14];
  const float* trans  = (const float*)d_in[15];

  char* ws = (char*)d_ws;
  // em/part overlap x's region (x is dead after k2; k3 no longer reads x)
  unsigned short* x     = (unsigned short*)(ws);                   // 16,777,216 B
  float*          em    = (float*)         (ws);                   //  2,359,296 B (after k3)
  float*          part  = (float*)         (ws + 2359296);         //        512 B
  unsigned short* Wih2  = (unsigned short*)(ws + 16777216);        //    524,288 B
  unsigned short* Whh2  = (unsigned short*)(ws + 17301504);        //    524,288 B
  float*          biasc = (float*)         (ws + 17825792);        //      4,096 B
  unsigned short* G     = (unsigned short*)(ws + 17829888);        // 134,217,728 B
  unsigned short* hs    = (unsigned short*)(ws + 152047616);       //  33,554,432 B -> ends 185,602,048

  hipLaunchKernelGGL(k0_prep,  dim3(1024), dim3(128), 0, stream,
                     Wihf, Whhf, bihf, bhhf, Wihb, Whhb, bihb, bhhb, Wih2, Whh2, biasc);
  hipLaunchKernelGGL(k1_embed, dim3(8192), dim3(256), 0, stream, chars, emb, x);
  hipLaunchKernelGGL(k2_gemm,  dim3(1024, 8), dim3(256), 0, stream, x, Wih2, biasc, G);
  hipLaunchKernelGGL(k3_scan2, dim3(16),   dim3(512), 0, stream, G, Whh2, hs);
  hipLaunchKernelGGL(k4_emis,  dim3(1024), dim3(512), 0, stream, hs, Wout, bout, em);
  hipLaunchKernelGGL(k5_crf,   dim3(128),  dim3(64),  0, stream,
                     em, chars, labels, startv, endv, trans, part);
  hipLaunchKernelGGL(k6_reduce, dim3(1),   dim3(128), 0, stream, part, (float*)d_out);
}

// Round 8
// 957.761 us; speedup vs baseline: 1.4418x; 1.0168x over previous
//
#include <hip/hip_runtime.h>

// Problem constants
#define B_   128
#define T_   512
#define EMB_ 128
#define H_   128
#define NL_  9
#define MT_  65536  // B*T

typedef __attribute__((ext_vector_type(8))) short short8v;
typedef __attribute__((ext_vector_type(4))) float float4v;

__device__ inline unsigned short f2bf(float f){
  unsigned u = __float_as_uint(f);
  u += 0x7FFFu + ((u >> 16) & 1u);          // round-to-nearest-even
  return (unsigned short)(u >> 16);
}
__device__ inline float bf2f(unsigned short s){
  return __uint_as_float(((unsigned)s) << 16);
}
__device__ inline float sigm(float x){ return 1.f / (1.f + __expf(-x)); }
__device__ inline float tanh_(float x){ return 2.f / (1.f + __expf(-2.f * x)) - 1.f; }

// fast primitives (v_exp_f32 = 2^x, v_rcp_f32 ~1ulp)
#define LOG2E 1.44269504f
__device__ inline float vexp2(float x){ float r; asm("v_exp_f32 %0, %1" : "=v"(r) : "v"(x)); return r; }
__device__ inline float vrcp (float x){ float r; asm("v_rcp_f32 %0, %1" : "=v"(r) : "v"(x)); return r; }

// one LSTM cell update from preactivations (combined-rcp form):
// sigm(i)*tanh(g) = (eg-1) * rcp((1+ei)(1+eg));  h = sigm(o)*tanh(c) likewise.
__device__ inline float lstm_cell(float pi, float pf, float pg, float po, float& c){
  float ei = vexp2(-LOG2E * pi);
  float ef = vexp2(-LOG2E * pf);
  float eg = vexp2( 2.f * LOG2E * pg);
  float eo = vexp2(-LOG2E * po);
  float R1 = vrcp((1.f + ei) * (1.f + eg));
  float ig = (eg - 1.f) * R1;
  float F  = vrcp(1.f + ef);
  c = fmaf(F, c, ig);
  float ec = vexp2(2.f * LOG2E * c);
  float R2 = vrcp((1.f + eo) * (1.f + ec));
  return (ec - 1.f) * R2;
}

__device__ inline void gload16(const void* g, void* l){
  __builtin_amdgcn_global_load_lds(
      (const __attribute__((address_space(1))) void*)g,
      (__attribute__((address_space(3)))       void*)l, 16, 0, 0);
}

// ---------------------------------------------------------------- K0: weight prep
// Row permutation nd = j*4 + g  (g: 0=i,1=f,2=g,3=o ; original row g*128+j).
__global__ void k0_prep(const float* __restrict__ Wihf, const float* __restrict__ Whhf,
                        const float* __restrict__ bihf, const float* __restrict__ bhhf,
                        const float* __restrict__ Wihb, const float* __restrict__ Whhb,
                        const float* __restrict__ bihb, const float* __restrict__ bhhb,
                        unsigned short* __restrict__ Wih2, unsigned short* __restrict__ Whh2,
                        float* __restrict__ biasc){
  int blk = blockIdx.x;            // 0..1023
  int dir = blk >> 9;
  int nd  = blk & 511;
  int k   = threadIdx.x;           // 0..127
  int j = nd >> 2, g = nd & 3;
  int orig = g * 128 + j;
  const float* Wih = dir ? Wihb : Wihf;
  const float* Whh = dir ? Whhb : Whhf;
  Wih2[((long)(dir * 512 + nd)) * 128 + k] = f2bf(Wih[orig * EMB_ + k]);
  Whh2[((long)(dir * 512 + nd)) * 128 + k] = f2bf(Whh[orig * H_ + k]);
  if (k == 0){
    const float* bi = dir ? bihb : bihf;
    const float* bh = dir ? bhhb : bhhf;
    biasc[dir * 512 + nd] = bi[orig] + bh[orig];
  }
}

// ---------------------------------------------------------------- K1: embedding gather -> bf16
__global__ void k1_embed(const int* __restrict__ chars, const float* __restrict__ emb,
                         unsigned short* __restrict__ x){
  int i = blockIdx.x * blockDim.x + threadIdx.x;
  int m = i >> 5, q = i & 31;
  int c = chars[m];
  const float4* e4 = (const float4*)(emb + (long)c * EMB_);
  float4 v = e4[q];
  ushort4 o;
  o.x = f2bf(v.x); o.y = f2bf(v.y); o.z = f2bf(v.z); o.w = f2bf(v.w);
  *(ushort4*)(x + (long)m * EMB_ + q * 4) = o;
}

// ---------------------------------------------------------------- K2: input projection GEMM (MFMA)
#define CST 130
__global__ __launch_bounds__(256) void k2_gemm(const unsigned short* __restrict__ x,
                                               const unsigned short* __restrict__ Wih2,
                                               const float* __restrict__ biasc,
                                               unsigned short* __restrict__ G){
  __shared__ unsigned short gsm[64 * CST];
  int w = threadIdx.x >> 6, lane = threadIdx.x & 63;
  int r = lane & 15, kb = (lane >> 4) * 8;
  long arow = (long)(blockIdx.x * 64 + w * 16 + r);
  short8v a[4];
  #pragma unroll
  for (int kf = 0; kf < 4; kf++)
    a[kf] = *(const short8v*)(x + arow * EMB_ + kf * 32 + kb);
  int ncol0 = blockIdx.y * 128;
  float4v acc[8];
  #pragma unroll
  for (int nf = 0; nf < 8; nf++){
    float4v z = {0.f, 0.f, 0.f, 0.f};
    acc[nf] = z;
    int wrow = ncol0 + nf * 16 + r;
    #pragma unroll
    for (int kf = 0; kf < 4; kf++){
      short8v bfrag = *(const short8v*)(Wih2 + (long)wrow * 128 + kf * 32 + kb);
      acc[nf] = __builtin_amdgcn_mfma_f32_16x16x32_bf16(a[kf], bfrag, acc[nf], 0, 0, 0);
    }
  }
  int rloc0 = w * 16 + (lane >> 4) * 4;
  #pragma unroll
  for (int nf = 0; nf < 8; nf++){
    int col = ncol0 + nf * 16 + r;
    float bia = biasc[col];
    #pragma unroll
    for (int reg = 0; reg < 4; reg++)
      gsm[(rloc0 + reg) * CST + nf * 16 + r] = f2bf(acc[nf][reg] + bia);
  }
  __syncthreads();
  #pragma unroll
  for (int it = 0; it < 4; it++){
    int u = it * 256 + threadIdx.x;
    int row = u >> 4, cu = u & 15;
    short8v v = *(const short8v*)&gsm[row * CST + cu * 8];
    *(short8v*)(G + (long)(blockIdx.x * 64 + row) * 1024 + ncol0 + cu * 8) = v;
  }
}

// ---------------------------------------------------------------- K3: recurrent scan, transposed MFMA
// 16 blocks x 1024 threads (16 waves, 4/SIMD). dir = blk>>3, rows [b0,b0+16).
// D[nd][m]: A = Whh frag (rows nd), B = h frag (rows m). Lane (q=l>>4, r=l&15):
// owns gates i,f,g,o of hidden j = 8w+4t+q at batch m=r (t = 0,1 tiles/wave).
// h ring hR[4] doubles as MFMA B-source (slot (s-1)&3) and output staging.
#define HBST 136   // 16B-aligned rows; b128 reads conflict-free ((r+q)%8 uniform)
#define GSTR 520   // Gpre LDS row stride (u16)
__global__ __launch_bounds__(1024, 1) void k3_scan3(
    const unsigned short* __restrict__ G,     // [B*T][1024] bf16 (bias included)
    const unsigned short* __restrict__ Whh2,  // [2][512 nd][128] bf16
    unsigned short* __restrict__ hs)          // [2][B*T][128] bf16
{
  const int blk = blockIdx.x;        // 0..15
  const int dir = blk >> 3;
  const int b0  = (blk & 7) * 16;
  const int tid = threadIdx.x;
  const int w   = tid >> 6;          // wave 0..15
  const int l   = tid & 63;
  const int r   = l & 15;            // = batch m owned in D, and A/B frag row
  const int q   = l >> 4;

  __shared__ unsigned short hR[4][16 * HBST];   // h ring (B-frags + output staging)
  __shared__ unsigned short Gl[2][16 * GSTR];   // Gpre tiles, dbuf

  // ---- Whh A-fragments: 2 tiles x 4 K-slices = 32 VGPR
  short8v Wf[2][4];
  #pragma unroll
  for (int t = 0; t < 2; t++){
    const unsigned short* wp = Whh2 + ((long)(dir * 512 + 32 * w + 16 * t + r)) * 128 + q * 8;
    #pragma unroll
    for (int kf = 0; kf < 4; kf++)
      Wf[t][kf] = *(const short8v*)(wp + kf * 32);
  }

  // zero ring slot 3 (h_init = 0, read by step 0)
  for (int i = tid; i < 16 * HBST; i += 1024) hR[3][i] = 0;

  float cc0 = 0.f, cc1 = 0.f;
  const int j0 = 8 * w + q;          // tile0 hidden index
  const int j1 = j0 + 4;             // tile1 hidden index

  // per-lane G source pointers (wave w stages batch row w, 1KB/step)
  const unsigned short* Gp0 = G + ((long)(b0 + w) * T_ + (dir ? T_ - 1 : 0)) * 1024
                                + dir * 512 + l * 8;
  const long gstep = (dir ? -1L : 1L) * 1024;
  const unsigned short* Gp = Gp0 + gstep;      // t for s=1

  gload16(Gp0, &Gl[0][w * GSTR]);              // prologue stage for s=0
  __syncthreads();

  for (int s = 0; s < T_; s++){
    const int p = s & 1;
    if (s + 1 < T_){                           // stage next step's Gpre
      gload16(Gp, &Gl[p ^ 1][w * GSTR]);
      Gp += gstep;
    }

    // B-frags: h from ring slot (s-1)&3
    const unsigned short* hrow = &hR[(s + 3) & 3][r * HBST + q * 8];
    short8v hf0 = *(const short8v*)(hrow);
    short8v hf1 = *(const short8v*)(hrow + 32);
    short8v hf2 = *(const short8v*)(hrow + 64);
    short8v hf3 = *(const short8v*)(hrow + 96);

    // acc init = gate preactivations (Wih*x + bias, from G)
    ushort4 gp0 = *(const ushort4*)&Gl[p][r * GSTR + 32 * w + 4 * q];
    ushort4 gp1 = *(const ushort4*)&Gl[p][r * GSTR + 32 * w + 16 + 4 * q];
    float4v acc0 = {bf2f(gp0.x), bf2f(gp0.y), bf2f(gp0.z), bf2f(gp0.w)};
    float4v acc1 = {bf2f(gp1.x), bf2f(gp1.y), bf2f(gp1.z), bf2f(gp1.w)};

    acc0 = __builtin_amdgcn_mfma_f32_16x16x32_bf16(Wf[0][0], hf0, acc0, 0, 0, 0);
    acc0 = __builtin_amdgcn_mfma_f32_16x16x32_bf16(Wf[0][1], hf1, acc0, 0, 0, 0);
    acc0 = __builtin_amdgcn_mfma_f32_16x16x32_bf16(Wf[0][2], hf2, acc0, 0, 0, 0);
    acc0 = __builtin_amdgcn_mfma_f32_16x16x32_bf16(Wf[0][3], hf3, acc0, 0, 0, 0);
    acc1 = __builtin_amdgcn_mfma_f32_16x16x32_bf16(Wf[1][0], hf0, acc1, 0, 0, 0);
    acc1 = __builtin_amdgcn_mfma_f32_16x16x32_bf16(Wf[1][1], hf1, acc1, 0, 0, 0);
    acc1 = __builtin_amdgcn_mfma_f32_16x16x32_bf16(Wf[1][2], hf2, acc1, 0, 0, 0);
    acc1 = __builtin_amdgcn_mfma_f32_16x16x32_bf16(Wf[1][3], hf3, acc1, 0, 0, 0);

    // gate nonlinearities + state update (gates i,f,g,o in acc regs 0..3)
    float hv0 = lstm_cell(acc0[0], acc0[1], acc0[2], acc0[3], cc0);
    float hv1 = lstm_cell(acc1[0], acc1[1], acc1[2], acc1[3], cc1);

    unsigned pk;
    asm("v_cvt_pk_bf16_f32 %0, %1, %2" : "=v"(pk) : "v"(hv0), "v"(hv1));
    unsigned short* wrow = &hR[s & 3][r * HBST];
    wrow[j0] = (unsigned short)pk;
    wrow[j1] = (unsigned short)(pk >> 16);
    __syncthreads();

    // coalesced flush of 4 steps of h (1 x 16B store per thread)
    if ((s & 3) == 3){
      int ii = tid >> 8, mm = (tid >> 4) & 15, j8 = tid & 15;
      int sg = s - 3 + ii;
      int tg = dir ? (T_ - 1 - sg) : sg;
      short8v v = *(const short8v*)&hR[ii][mm * HBST + j8 * 8];
      *(short8v*)(hs + ((long)dir * MT_ + (long)(b0 + mm) * T_ + tg) * H_ + j8 * 8) = v;
      __syncthreads();
    }
  }
}

// ---------------------------------------------------------------- K4: emissions = [hf,hb] @ Wout^T + bout
#define HSTR 264
__global__ __launch_bounds__(512) void k4_emis(const unsigned short* __restrict__ hs,
                                               const float* __restrict__ Wout,
                                               const float* __restrict__ bout,
                                               float* __restrict__ em){
  __shared__ float hcat[64 * HSTR];
  __shared__ float wo[NL_ * 256];
  int tid = threadIdx.x;
  int m0 = blockIdx.x * 64;
  const unsigned short* hf = hs;
  const unsigned short* hb = hs + (long)MT_ * H_;
  #pragma unroll
  for (int it = 0; it < 8; it++){
    int flat = it * 2048 + tid * 4;
    int r = flat >> 8, u = flat & 255;
    const unsigned short* src = (u < 128) ? (hf + (long)(m0 + r) * H_ + u)
                                          : (hb + (long)(m0 + r) * H_ + (u - 128));
    ushort4 v = *(const ushort4*)src;
    hcat[r * HSTR + u]     = bf2f(v.x);
    hcat[r * HSTR + u + 1] = bf2f(v.y);
    hcat[r * HSTR + u + 2] = bf2f(v.z);
    hcat[r * HSTR + u + 3] = bf2f(v.w);
  }
  for (int f = tid; f < NL_ * 256; f += 512) wo[f] = Wout[f];
  __syncthreads();
  #pragma unroll
  for (int half = 0; half < 2; half++){
    int idx = half * 512 + tid;
    if (idx < 64 * NL_){
      int r = idx / NL_, lbl = idx % NL_;
      float acc = bout[lbl];
      #pragma unroll 8
      for (int u = 0; u < 256; u++)
        acc = fmaf(hcat[r * HSTR + u], wo[lbl * 256 + u], acc);
      em[(long)(m0 + r) * NL_ + lbl] = acc;
    }
  }
}

// ---------------------------------------------------------------- K5: CRF NLL per sequence
__global__ void k5_crf(const float* __restrict__ em, const int* __restrict__ chars,
                       const int* __restrict__ labels, const float* __restrict__ startv,
                       const float* __restrict__ endv, const float* __restrict__ trans,
                       float* __restrict__ partial){
  int b = blockIdx.x, lane = threadIdx.x;   // 64 threads (1 wave)
  const int* lab = labels + b * T_;
  const int* ch  = chars + b * T_;
  const float* e = em + (long)b * T_ * NL_;
  float sc = 0.f; int cnt = 0;
  for (int t = lane; t < T_; t += 64){
    int m = (ch[t] != 0);
    cnt += m;
    if (m){
      sc += e[t * NL_ + lab[t]];
      if (t > 0) sc += trans[lab[t - 1] * NL_ + lab[t]];
    }
  }
  #pragma unroll
  for (int off = 32; off; off >>= 1){
    sc  += __shfl_down(sc, off);
    cnt += __shfl_down(cnt, off);
  }
  sc  = __shfl(sc, 0);
  cnt = __shfl(cnt, 0);
  if (cnt < 1) cnt = 1;
  int jl = (lane < NL_) ? lane : 0;
  float tcol[NL_];
  #pragma unroll
  for (int i = 0; i < NL_; i++) tcol[i] = trans[i * NL_ + jl];
  float alpha = (lane < NL_) ? (startv[jl] + e[jl]) : -1e30f;
  float evn = (lane < NL_) ? e[NL_ + jl] : 0.f;
  int   mn  = (ch[1] != 0);
  for (int t = 1; t < T_; t++){
    float ev = evn; int m = mn;
    int t2 = (t + 1 < T_) ? t + 1 : t;
    evn = (lane < NL_) ? e[t2 * NL_ + jl] : 0.f;
    mn  = (ch[t2] != 0);
    float vv[NL_]; float mx = -1e30f;
    #pragma unroll
    for (int i = 0; i < NL_; i++){
      vv[i] = __shfl(alpha, i) + tcol[i];
      mx = fmaxf(mx, vv[i]);
    }
    float ssum = 0.f;
    #pragma unroll
    for (int i = 0; i < NL_; i++) ssum += __expf(vv[i] - mx);
    float nxt = mx + __logf(ssum) + ev;
    if (m && lane < NL_) alpha = nxt;
  }
  float av = (lane < NL_) ? (alpha + endv[jl]) : -1e30f;
  float mx = av;
  #pragma unroll
  for (int off = 8; off; off >>= 1) mx = fmaxf(mx, __shfl_down(mx, off));
  mx = __shfl(mx, 0);
  float ex = (lane < NL_) ? __expf(av - mx) : 0.f;
  #pragma unroll
  for (int off = 8; off; off >>= 1) ex += __shfl_down(ex, off);
  if (lane == 0){
    float logZ = mx + __logf(ex);
    float score = sc + startv[lab[0]] + endv[lab[cnt - 1]];
    partial[b] = logZ - score;
  }
}

// ---------------------------------------------------------------- K6: deterministic final reduce
__global__ void k6_reduce(const float* __restrict__ partial, float* __restrict__ out){
  int lane = threadIdx.x;  // 128 threads
  float v = partial[lane];
  #pragma unroll
  for (int off = 32; off; off >>= 1) v += __shfl_down(v, off);
  __shared__ float tmp[2];
  if ((lane & 63) == 0) tmp[lane >> 6] = v;
  __syncthreads();
  if (lane == 0) out[0] = tmp[0] + tmp[1];
}

// ---------------------------------------------------------------- launch
extern "C" void kernel_launch(void* const* d_in, const int* in_sizes, int n_in,
                              void* d_out, int out_size, void* d_ws, size_t ws_size,
                              hipStream_t stream){
  const int*   chars  = (const int*)d_in[0];
  const int*   labels = (const int*)d_in[1];
  const float* emb    = (const float*)d_in[2];
  const float* Wihf   = (const float*)d_in[3];
  const float* Whhf   = (const float*)d_in[4];
  const float* bihf   = (const float*)d_in[5];
  const float* bhhf   = (const float*)d_in[6];
  const float* Wihb   = (const float*)d_in[7];
  const float* Whhb   = (const float*)d_in[8];
  const float* bihb   = (const float*)d_in[9];
  const float* bhhb   = (const float*)d_in[10];
  const float* Wout   = (const float*)d_in[11];
  const float* bout   = (const float*)d_in[12];
  const float* startv = (const float*)d_in[13];
  const float* endv   = (const float*)d_in[14];
  const float* trans  = (const float*)d_in[15];

  char* ws = (char*)d_ws;
  unsigned short* x     = (unsigned short*)(ws);                   // 16,777,216 B
  float*          em    = (float*)         (ws);                   //  2,359,296 B (after k3)
  float*          part  = (float*)         (ws + 2359296);         //        512 B
  unsigned short* Wih2  = (unsigned short*)(ws + 16777216);        //    524,288 B
  unsigned short* Whh2  = (unsigned short*)(ws + 17301504);        //    524,288 B
  float*          biasc = (float*)         (ws + 17825792);        //      4,096 B
  unsigned short* G     = (unsigned short*)(ws + 17829888);        // 134,217,728 B
  unsigned short* hs    = (unsigned short*)(ws + 152047616);       //  33,554,432 B

  hipLaunchKernelGGL(k0_prep,  dim3(1024), dim3(128), 0, stream,
                     Wihf, Whhf, bihf, bhhf, Wihb, Whhb, bihb, bhhb, Wih2, Whh2, biasc);
  hipLaunchKernelGGL(k1_embed, dim3(8192), dim3(256), 0, stream, chars, emb, x);
  hipLaunchKernelGGL(k2_gemm,  dim3(1024, 8), dim3(256), 0, stream, x, Wih2, biasc, G);
  hipLaunchKernelGGL(k3_scan3, dim3(16),   dim3(1024), 0, stream, G, Whh2, hs);
  hipLaunchKernelGGL(k4_emis,  dim3(1024), dim3(512), 0, stream, hs, Wout, bout, em);
  hipLaunchKernelGGL(k5_crf,   dim3(128),  dim3(64),  0, stream,
                     em, chars, labels, startv, endv, trans, part);
  hipLaunchKernelGGL(k6_reduce, dim3(1),   dim3(128), 0, stream, part, (float*)d_out);
}